// Round 9
// baseline (18909.827 us; speedup 1.0000x reference)
//
#include <hip/hip_runtime.h>

// LSTM: I=512, H=2048, O=512, T=4096, batch=1, fp32.
// Phase 1: xz[T][4H] = input @ W_ih^T + (b_ih + b_hh)   (tiled fp32 GEMM)
// Phase 2: persistent plain-launch kernel (256 blocks = 256 CUs co-resident,
//          launch_bounds(256,1)), W_hh register/AGPR-resident.
//          R9: wave-autonomous quarters. Wave q of each block owns h-quarter
//          q end-to-end: waits its 64 producer flags, loads its 512 h values
//          once, stages into a wave-PRIVATE LDS strip (no barrier), and runs
//          its partial matvec immediately (chunks 2q, 2q+1). One
//          __syncthreads per step, before the cross-wave reduce. Wave 0
//          reduces partials + xz, applies gates (c-state in registers),
//          stores the block's 8 h values, drains ONLY its own stores
//          (s_waitcnt on wave 0; xz prefetch moved after the flag store so
//          it is off the drain path), then publishes the flag. Waves 1-3
//          poll step t+1 while wave 0 finishes the tail.
// Phase 3: out = W_lin @ h_T + b_lin.

#define TSTEPS 4096
#define HDIM   2048
#define GDIM   8192   // 4H
#define IDIM   512
#define ODIM   512

#define XZ_BYTES ((size_t)TSTEPS * GDIM * sizeof(float))   // 128 MB
#define FLAG_STRIDE 16   // unsigned slots per block flag: 64B line pitch

__device__ __forceinline__ float sigmoidf_fast(float x) {
    return 1.0f / (1.0f + __expf(-x));
}
__device__ __forceinline__ float tanhf_fast(float x) {
    return 2.0f / (1.0f + __expf(-2.0f * x)) - 1.0f;
}

// ---------------------------------------------------------------------------
// Phase 1: C[4096][8192] = A[4096][512] * B[8192][512]^T + (bih+bhh)[n]
// 128x128 block tile, BK=16, 256 threads, 8x8 per thread.
// ---------------------------------------------------------------------------
__global__ __launch_bounds__(256) void xz_gemm(
    const float* __restrict__ A, const float* __restrict__ B,
    const float* __restrict__ bih, const float* __restrict__ bhh,
    float* __restrict__ C)
{
    __shared__ float As[16][132];
    __shared__ float Bs[16][132];

    const int tid = threadIdx.x;
    const int m0 = blockIdx.y * 128;
    const int n0 = blockIdx.x * 128;
    const int tx = tid & 15;        // n-direction
    const int ty = tid >> 4;        // m-direction

    const int lrow  = tid >> 1;          // 0..127
    const int kbase = (tid & 1) * 8;     // k offset 0 or 8

    float acc[8][8] = {};

    for (int k0 = 0; k0 < IDIM; k0 += 16) {
        const float4 av0 = *(const float4*)(A + (size_t)(m0 + lrow) * IDIM + k0 + kbase);
        const float4 av1 = *(const float4*)(A + (size_t)(m0 + lrow) * IDIM + k0 + kbase + 4);
        const float4 bv0 = *(const float4*)(B + (size_t)(n0 + lrow) * IDIM + k0 + kbase);
        const float4 bv1 = *(const float4*)(B + (size_t)(n0 + lrow) * IDIM + k0 + kbase + 4);

        __syncthreads();   // previous tile fully consumed
        As[kbase + 0][lrow] = av0.x; As[kbase + 1][lrow] = av0.y;
        As[kbase + 2][lrow] = av0.z; As[kbase + 3][lrow] = av0.w;
        As[kbase + 4][lrow] = av1.x; As[kbase + 5][lrow] = av1.y;
        As[kbase + 6][lrow] = av1.z; As[kbase + 7][lrow] = av1.w;
        Bs[kbase + 0][lrow] = bv0.x; Bs[kbase + 1][lrow] = bv0.y;
        Bs[kbase + 2][lrow] = bv0.z; Bs[kbase + 3][lrow] = bv0.w;
        Bs[kbase + 4][lrow] = bv1.x; Bs[kbase + 5][lrow] = bv1.y;
        Bs[kbase + 6][lrow] = bv1.z; Bs[kbase + 7][lrow] = bv1.w;
        __syncthreads();

#pragma unroll
        for (int kk = 0; kk < 16; ++kk) {
            const float4 a0 = *(const float4*)&As[kk][ty * 8];
            const float4 a1 = *(const float4*)&As[kk][ty * 8 + 4];
            const float4 b0 = *(const float4*)&Bs[kk][tx * 8];
            const float4 b1 = *(const float4*)&Bs[kk][tx * 8 + 4];
            const float ar[8] = {a0.x, a0.y, a0.z, a0.w, a1.x, a1.y, a1.z, a1.w};
            const float br[8] = {b0.x, b0.y, b0.z, b0.w, b1.x, b1.y, b1.z, b1.w};
#pragma unroll
            for (int i = 0; i < 8; ++i)
#pragma unroll
                for (int jj = 0; jj < 8; ++jj)
                    acc[i][jj] = fmaf(ar[i], br[jj], acc[i][jj]);
        }
    }

    float bias[8];
#pragma unroll
    for (int jj = 0; jj < 8; ++jj) {
        const int n = n0 + tx * 8 + jj;
        bias[jj] = bih[n] + bhh[n];
    }
#pragma unroll
    for (int i = 0; i < 8; ++i) {
        float* crow = C + (size_t)(m0 + ty * 8 + i) * GDIM + n0 + tx * 8;
        float4 v0, v1;
        v0.x = acc[i][0] + bias[0]; v0.y = acc[i][1] + bias[1];
        v0.z = acc[i][2] + bias[2]; v0.w = acc[i][3] + bias[3];
        v1.x = acc[i][4] + bias[4]; v1.y = acc[i][5] + bias[5];
        v1.z = acc[i][6] + bias[6]; v1.w = acc[i][7] + bias[7];
        ((float4*)crow)[0] = v0;
        ((float4*)crow)[1] = v1;
    }
}

// ---------------------------------------------------------------------------
// Phase 2: persistent recurrent kernel. 256 blocks x 256 threads, plain
// launch (co-resident at 1 block/CU, launch_bounds(256,1)).
// Block b computes j in [8b, 8b+8) for all 4 gates.
// Thread (wv, ln): sub = ln>>5, ck = 2*wv + sub (k-chunk [256ck,256ck+256));
//                  go = ln&31, gq = go>>3 (gate), jo = go&7 (j offset).
// Each thread: 256 W_hh weights (64 float4, AGPR-resident) for
// row = gq*H + 8b + jo. Wave wv's chunks {2wv,2wv+1} = h-quarter wv,
// produced by blocks [64wv, 64wv+64) (flags 1/lane).
// Cross-wave reduce via LDS part[parity][4][32]; wave 0 applies gates,
// stores 8 h (lanes 0-7), short drain, publishes flag.
// Overwrite safety (unchanged): flag=t+1 stored only after all waves passed
// sync_t, i.e. after every wave consumed its h_t quarter. Max skew 1 step.
// ---------------------------------------------------------------------------
__global__ __launch_bounds__(256, 1) void lstm_rec(
    const float* __restrict__ Whh, const float* __restrict__ xz,
    float* __restrict__ hbuf, unsigned* __restrict__ flags)
{
    __shared__ float hsh[4 * 520];        // wave-private strips (520 stride)
    __shared__ float part[2][4][32];      // parity-buffered partials

    const int tidb = threadIdx.x;
    const int b    = blockIdx.x;
    const int wv   = tidb >> 6;    // wave 0..3 == h-quarter this wave owns
    const int ln   = tidb & 63;    // lane
    const int sub  = ln >> 5;      // 0/1
    const int ck   = 2 * wv + sub; // k-chunk
    const int go   = ln & 31;      // (gate, j-offset) id
    const int gq   = go >> 3;      // gate 0..3 (i,f,g,o)
    const int jo   = go & 7;       // j offset 0..7
    const int j0   = 8 * b;
    const int row  = gq * HDIM + j0 + jo;

    // one-time weight load into registers/AGPRs (64 MB total across grid)
    const float4* wsrc = (const float4*)(Whh + (size_t)row * HDIM) + ck * 64;
    float4 w[64];
#pragma unroll
    for (int i = 0; i < 64; ++i) w[i] = wsrc[i];

    float cstate = 0.0f;          // valid on wave 0 lanes 0..7

    // this wave's producer flag (1 per lane): blocks [64wv, 64wv+64)
    const unsigned* myflag = flags + (size_t)(wv * 64 + ln) * FLAG_STRIDE;

    // xz is consumed ONLY by wave 0 (the reducer): one value per go
    float zx = 0.0f;
    if (wv == 0) zx = xz[row];    // xz[0][row(go)]

    for (int t = 0; t < TSTEPS; ++t) {
        const int p = t & 1;

        // ---- wait: my quarter's 64 producers finished step t-1 ----
        {
            const unsigned need = (unsigned)t;
            unsigned spins = 0;
            while (__hip_atomic_load(myflag, __ATOMIC_RELAXED,
                                     __HIP_MEMORY_SCOPE_AGENT) < need) {
                __builtin_amdgcn_s_sleep(1);
                if (++spins > (1u << 22)) break;   // fail fast, no hang
            }
        }

        // ---- load my 512-value h-quarter ONCE (coalesced, 8/lane) ----
        const float* hsrc = hbuf + (p << 11) + wv * 512;
        float hv[8];
#pragma unroll
        for (int m = 0; m < 8; ++m)
            hv[m] = __hip_atomic_load(hsrc + m * 64 + ln, __ATOMIC_RELAXED,
                                      __HIP_MEMORY_SCOPE_AGENT);

        // ---- stage into wave-PRIVATE strip (no cross-wave barrier) ----
#pragma unroll
        for (int m = 0; m < 8; ++m)
            hsh[wv * 520 + m * 64 + ln] = hv[m];
        // intra-wave lgkmcnt ordering is compiler-inserted before the reads

        // ---- partial matvec over my 256-k slice ----
        const float4* hr = (const float4*)(hsh + wv * 520 + sub * 256);
        float a0 = 0.f, a1 = 0.f, a2 = 0.f, a3 = 0.f;
#pragma unroll
        for (int i = 0; i < 64; ++i) {
            const float4 h4 = hr[i];
            a0 = fmaf(w[i].x, h4.x, a0);
            a1 = fmaf(w[i].y, h4.y, a1);
            a2 = fmaf(w[i].z, h4.z, a2);
            a3 = fmaf(w[i].w, h4.w, a3);
        }
        float d = (a0 + a1) + (a2 + a3);
        d += __shfl_xor(d, 32);           // combine sub-chunks: quarter sum
        if (ln < 32) part[p][wv][ln] = d; // per-wave partial for (gq,jo)

        __syncthreads();   // the ONLY block-wide sync per step

        if (wv == 0) {
            // ---- reduce 4 quarters + xz, apply gates (lanes 0..31) ----
            const float z = part[p][0][go] + part[p][1][go] +
                            part[p][2][go] + part[p][3][go] + zx;
            const float zf = __shfl(z,  8 + jo);
            const float zg = __shfl(z, 16 + jo);
            const float zo = __shfl(z, 24 + jo);
            if (ln < 8) {    // lane jo: z is gate i for j = j0+jo
                const float ig = sigmoidf_fast(z);
                const float fg = sigmoidf_fast(zf);
                const float gg = tanhf_fast(zg);
                const float og = sigmoidf_fast(zo);
                cstate = fmaf(fg, cstate, ig * gg);
                const float hval = og * tanhf_fast(cstate);
                __hip_atomic_store(hbuf + (((t + 1) & 1) << 11) + j0 + jo,
                                   hval, __ATOMIC_RELAXED,
                                   __HIP_MEMORY_SCOPE_AGENT);
            }
            // drain ONLY wave 0's stores (xz prefetch is issued after this)
            __builtin_amdgcn_s_waitcnt(0);
            if (ln == 0)
                __hip_atomic_store(flags + (size_t)b * FLAG_STRIDE,
                                   (unsigned)(t + 1), __ATOMIC_RELAXED,
                                   __HIP_MEMORY_SCOPE_AGENT);
            // prefetch next xz row — off the drain path now
            const int tn = (t + 1 < TSTEPS) ? (t + 1) : (TSTEPS - 1);
            zx = xz[(size_t)tn * GDIM + row];
        }
        // waves 1-3 loop immediately: they poll step t+1 flags while wave 0
        // finishes the reduce/store/flag tail.
    }
}

// ---------------------------------------------------------------------------
// Phase 3: out[512] = W_lin[512][2048] @ h_T + b_lin. One wave per output.
// h_T = h_4096 lives in hbuf parity 0 (4096 & 1 == 0).
// ---------------------------------------------------------------------------
__global__ __launch_bounds__(256) void final_linear(
    const float* __restrict__ Wlin, const float* __restrict__ blin,
    const float* __restrict__ hT, float* __restrict__ out)
{
    const int wid  = (blockIdx.x * 256 + threadIdx.x) >> 6;   // 0..511
    const int lane = threadIdx.x & 63;
    const float4* wr = (const float4*)(Wlin + (size_t)wid * HDIM);
    const float4* hp = (const float4*)hT;
    float acc = 0.f;
#pragma unroll
    for (int i = 0; i < 8; ++i) {
        const float4 w4 = wr[lane + 64 * i];
        const float4 h4 = hp[lane + 64 * i];
        acc += w4.x * h4.x + w4.y * h4.y + w4.z * h4.z + w4.w * h4.w;
    }
#pragma unroll
    for (int off = 32; off > 0; off >>= 1) acc += __shfl_down(acc, off);
    if (lane == 0) out[wid] = acc + blin[wid];
}

extern "C" void kernel_launch(void* const* d_in, const int* in_sizes, int n_in,
                              void* d_out, int out_size, void* d_ws, size_t ws_size,
                              hipStream_t stream) {
    const float* input = (const float*)d_in[0];   // [4096][512]
    const float* Wih   = (const float*)d_in[1];   // [8192][512]
    const float* Whh   = (const float*)d_in[2];   // [8192][2048]
    const float* bih   = (const float*)d_in[3];   // [8192]
    const float* bhh   = (const float*)d_in[4];   // [8192]
    const float* Wlin  = (const float*)d_in[5];   // [512][2048]
    const float* blin  = (const float*)d_in[6];   // [512]
    float* out = (float*)d_out;                   // [512]

    char* ws = (char*)d_ws;
    float*    xz    = (float*)ws;                                   // 128 MB
    float*    hbuf  = (float*)(ws + XZ_BYTES);                      // 2 x 2048 fp32
    unsigned* flags = (unsigned*)(ws + XZ_BYTES + 2 * HDIM * sizeof(float)); // 256*64B

    // zero h buffers + flags (ws is poisoned 0xAA before every launch);
    // flags=0 == "0 steps completed" == h_0 (zeros) valid.
    hipMemsetAsync(hbuf, 0,
                   2 * HDIM * sizeof(float) + 256 * FLAG_STRIDE * sizeof(unsigned),
                   stream);

    dim3 ggrid(GDIM / 128, TSTEPS / 128);   // (64, 32)
    xz_gemm<<<ggrid, 256, 0, stream>>>(input, Wih, bih, bhh, xz);

    // plain launch: 256 blocks, 1 block/CU => all co-resident on 256 CUs.
    lstm_rec<<<dim3(256), dim3(256), 0, stream>>>(Whh, xz, hbuf, flags);

    final_linear<<<ODIM / 4, 256, 0, stream>>>(Wlin, blin, hbuf, out);
}